// Round 12
// baseline (149.483 us; speedup 1.0000x reference)
//
#include <hip/hip_runtime.h>
#include <hip/hip_bf16.h>
#include <stdint.h>

#define N    8192
#define D    256
#define NCLS 100

static constexpr float TEMP    = 0.5f;
static constexpr float SCALE_F = 1.69864360f;  // sqrt(log2e/TEMP)
static constexpr float LN2     = 0.69314718055994531f;

// Partial slots (R12, 128-row bands, 64 bands, NSLOT=192):
//   row-side: block (y,s), wave col-half jh -> slot 2s+jh      (0..63)
//   col-side: tile col-band x, writer block (y,s) wave row-half wh
//             -> slot 64 + 2y + wh                              (64..191)
// Exact coverage (every slot in the finalize ranges written exactly once);
// finalize uses per-band variable slot counts -> no zero-fill, no atomics.
#define NSLOT 192

typedef float f32x4 __attribute__((ext_vector_type(4)));
typedef long  lx2  __attribute__((ext_vector_type(2)));

__device__ __forceinline__ unsigned short f2bf(float f) {
  union { float f; unsigned int u; } x; x.f = f;
  unsigned int r = x.u + 0x7fffu + ((x.u >> 16) & 1u);
  return (unsigned short)(r >> 16);
}
__device__ __forceinline__ float bf2f(unsigned short b) {
  union { unsigned int u; float f; } x; x.u = ((unsigned int)b) << 16;
  return x.f;
}

// fp8 fragment-PAIR-major layout: for row r, k:
//   kq = k>>6, kl = k&63, kkl = kl>>5, q = (kl>>3)&3
//   addr = (r>>4)*4096 + kq*1024 + q*256 + (r&15)*16 + kkl*8 + (k&7)
// -> lane (quad,l15)'s fragments for BOTH kkl halves of one kq are one
//    contiguous 16B: global_load_dwordx4, wave-contiguous 1024B segment.

// ---- Kernel A: row-normalize; bf16 row-major copy (class sums) + fp8 e4m3
// fragment-pair-major copy (GEMM).
__global__ __launch_bounds__(256) void normalize_kernel(
    const float* __restrict__ emb, const long long* __restrict__ label,
    unsigned short* __restrict__ abf, unsigned char* __restrict__ a8,
    int* __restrict__ cnt, int* __restrict__ list) {
  const int row  = blockIdx.x * 4 + (threadIdx.x >> 6);
  const int lane = threadIdx.x & 63;
  const float4 v = ((const float4*)(emb + (size_t)row * D))[lane];
  float ss = v.x * v.x + v.y * v.y + v.z * v.z + v.w * v.w;
#pragma unroll
  for (int off = 1; off < 64; off <<= 1) ss += __shfl_xor(ss, off);
  const float s = rsqrtf(ss) * SCALE_F;
  const float x = v.x * s, y = v.y * s, z = v.z * s, wv = v.w * s;

  ushort4 o;
  o.x = f2bf(x); o.y = f2bf(y); o.z = f2bf(z); o.w = f2bf(wv);
  ((ushort4*)(abf + (size_t)row * D))[lane] = o;

  int p = __builtin_amdgcn_cvt_pk_fp8_f32(x, y, 0, false);
  p = __builtin_amdgcn_cvt_pk_fp8_f32(z, wv, p, true);
  // k0 = lane*4: kq=lane>>4, q=(lane>>1)&3, kkl=(lane>>3)&1, k&7=(lane&1)*4
  *(int*)(a8 + (size_t)(row >> 4) * 4096 + (lane >> 4) * 1024 +
          ((lane >> 1) & 3) * 256 + (row & 15) * 16 + ((lane >> 3) & 1) * 8 +
          (lane & 1) * 4) = p;

  if (lane == 0) {
    const int c = (int)label[row];
    const int slot = atomicAdd(cnt + c, 1);
    list[c * 256 + slot] = row;
  }
}

// ---- Kernel B: symmetric (strict upper triangle). One block per 2-tile
// STRIP: band y (128 rows) x strip s covering col-tiles x = y+2s, y+2s+1.
// 1056 blocks, 256 threads, all operands in registers, no LDS, no barriers.
//
// R12 theory (issued-bytes wall): across R1-R11 the only model that fits
// is a per-CU issued-load-byte ceiling of ~15 B/cyc (R8: 272 MB -> 30 us;
// matches m13/m97 per-CU rates). Register-A reuse across 2 B-tiles cuts
// issued bytes 25% (192 KB/block x 1056 = 203 MB) while keeping the
// proven R8 skeleton (pure reg, 2 blocks/CU co-resident, no sync).
__global__ __launch_bounds__(256, 2) void simexp_rowsum_kernel(
    const unsigned char* __restrict__ A, float* __restrict__ part) {
  const int tid  = threadIdx.x;
  const int w    = tid >> 6;
  const int lane = tid & 63;
  const int quad = lane >> 4;
  const int l15  = lane & 15;

  // Strip decode: band y has (65-y)>>1 strips; cum over y.
  const int b = blockIdx.x;
  int y = 0, c = 0;
  while (c + ((65 - y) >> 1) <= b) { c += (65 - y) >> 1; ++y; }
  const int s = b - c;

  const int wm  = (w & 1) * 64;   // wave's row half within the band
  const int jn0 = (w >> 1) * 64;  // wave's col half within a tile
  const int jh  = jn0 >> 6;
  const int wh  = wm >> 6;
  const bool diagstrip = (s == 0);  // tile 0 of strip 0 is the diagonal tile

  const unsigned char* Ap = A + (size_t)(y * 8 + (w & 1) * 4) * 4096;
  const int lo = quad * 256 + l15 * 16;

  // A fragments: loaded once, reused for both tiles (the whole point).
  lx2 aF[4][4];
#pragma unroll
  for (int mt = 0; mt < 4; ++mt)
#pragma unroll
    for (int kq = 0; kq < 4; ++kq)
      aF[mt][kq] = *(const lx2*)(Ap + mt * 4096 + kq * 1024 + lo);

  float rowpart[4][4];
#pragma unroll
  for (int mt = 0; mt < 4; ++mt)
#pragma unroll
    for (int e = 0; e < 4; ++e) rowpart[mt][e] = 0.f;

#pragma unroll
  for (int t = 0; t < 2; ++t) {
    const int x = y + 2 * s + t;
    if (x >= 64) break;  // odd-length band: last strip has one tile

    const unsigned char* Bp = A + (size_t)(x * 8 + (w >> 1) * 4) * 4096;
    lx2 bF[4][4];
#pragma unroll
    for (int nt = 0; nt < 4; ++nt)
#pragma unroll
      for (int kq = 0; kq < 4; ++kq)
        bF[nt][kq] = *(const lx2*)(Bp + nt * 4096 + kq * 1024 + lo);

    f32x4 acc[4][4];
#pragma unroll
    for (int mt = 0; mt < 4; ++mt)
#pragma unroll
      for (int nt = 0; nt < 4; ++nt)
        acc[mt][nt] = (f32x4){0.f, 0.f, 0.f, 0.f};

#pragma unroll
    for (int kq = 0; kq < 4; ++kq)
#pragma unroll
      for (int kkl = 0; kkl < 2; ++kkl)
#pragma unroll
        for (int mt = 0; mt < 4; ++mt)
#pragma unroll
          for (int nt = 0; nt < 4; ++nt)
            acc[mt][nt] = __builtin_amdgcn_mfma_f32_16x16x32_fp8_fp8(
                aF[mt][kq][kkl], bF[nt][kq][kkl], acc[mt][nt], 0, 0, 0);

    // Epilogue for this tile: exp2, diagonal mask (handles all three wave
    // quadrants of the diag tile via iw<jw), row + col partials.
    const bool dmask = diagstrip && (t == 0);
    float colpart[4] = {0.f, 0.f, 0.f, 0.f};
#pragma unroll
    for (int mt = 0; mt < 4; ++mt)
#pragma unroll
      for (int nt = 0; nt < 4; ++nt)
#pragma unroll
        for (int e = 0; e < 4; ++e) {
          float v = __builtin_amdgcn_exp2f(acc[mt][nt][e]);
          if (dmask) {
            const int iw = wm + mt * 16 + quad * 4 + e;   // row in 128-tile
            const int jw = jn0 + nt * 16 + l15;           // col in 128-tile
            v = (iw < jw) ? v : 0.f;
          }
          rowpart[mt][e] += v;
          colpart[nt] += v;
        }

    // Column store for this tile: band x, slot 64 + 2y + wh.
    float* coldst = part + ((size_t)x * NSLOT + 64 + 2 * y + wh) * 128 + jn0;
#pragma unroll
    for (int nt = 0; nt < 4; ++nt) {
      float v = colpart[nt];
      v += __shfl_xor(v, 16);
      v += __shfl_xor(v, 32);
      if (quad == 0) coldst[nt * 16 + l15] = v;
    }
  }

  // Row store (accumulated over both tiles): band y, slot 2s + jh.
  float* rowdst = part + ((size_t)y * NSLOT + 2 * s + jh) * 128 + wm;
#pragma unroll
  for (int mt = 0; mt < 4; ++mt)
#pragma unroll
    for (int e = 0; e < 4; ++e) {
      float v = rowpart[mt][e];
      v += __shfl_xor(v, 1);
      v += __shfl_xor(v, 2);
      v += __shfl_xor(v, 4);
      v += __shfl_xor(v, 8);
      if (l15 == 0) rowdst[mt * 16 + quad * 4 + e] = v;
    }
}

__global__ __launch_bounds__(256) void finalize_kernel(
    const unsigned short* __restrict__ abf, const float* __restrict__ part,
    const long long* __restrict__ label, const int* __restrict__ cnt,
    const int* __restrict__ list, float* __restrict__ out) {
  __shared__ float red[4];
  __shared__ int rows_l[256];
  const int tid  = threadIdx.x;
  const int w    = tid >> 6;
  const int lane = tid & 63;

  if (blockIdx.x < NCLS) {
    const int c = blockIdx.x;
    const int m = cnt[c];
    if (m <= 1) return;
    if (tid < m) rows_l[tid] = list[c * 256 + tid];
    __syncthreads();
    float acc = 0.f;
    for (int s = 0; s < m; ++s)
      acc += bf2f(abf[(size_t)rows_l[s] * D + tid]);
    float v = acc * acc;
#pragma unroll
    for (int off = 1; off < 64; off <<= 1) v += __shfl_xor(v, off);
    if (lane == 0) red[w] = v;
    __syncthreads();
    if (tid == 0) {
      const float ssq = red[0] + red[1] + red[2] + red[3];
      const float term = (ssq * LN2 - 2.0f * (float)m) / (float)(m - 1);
      atomicAdd(out, -term);
    }
  } else {
    // rowsum_i = sum of this band's written partial slots:
    //   row-side: 2*strips(band) slots from 0; col-side: 2*band+2 from 64.
    const int i = (blockIdx.x - NCLS) * 256 + tid;
    const int band = i >> 7, r = i & 127;
    const float* ps = part + (size_t)band * NSLOT * 128 + r;
    const int rs_n = 2 * ((65 - band) >> 1);
    const int cs_n = 2 * band + 2;
    float rs = 0.f;
    for (int s2 = 0; s2 < rs_n; ++s2) rs += ps[(size_t)s2 * 128];
    for (int u = 0; u < cs_n; ++u) rs += ps[(size_t)(64 + u) * 128];
    const int c = (int)label[i];
    float v = 0.f;
    if (cnt[c] > 1)
      v = __builtin_amdgcn_logf(rs) * LN2;
#pragma unroll
    for (int off = 1; off < 64; off <<= 1) v += __shfl_xor(v, off);
    if (lane == 0) red[w] = v;
    __syncthreads();
    if (tid == 0)
      atomicAdd(out, red[0] + red[1] + red[2] + red[3]);
  }
}

extern "C" void kernel_launch(void* const* d_in, const int* in_sizes, int n_in,
                              void* d_out, int out_size, void* d_ws,
                              size_t ws_size, hipStream_t stream) {
  const float* emb = (const float*)d_in[0];
  const long long* label = (const long long*)d_in[1];
  float* out = (float*)d_out;

  char* ws = (char*)d_ws;
  unsigned short* abf = (unsigned short*)ws;            // 4 MB bf16 row-major
  unsigned char* a8 = (unsigned char*)(ws + (size_t)N * D * 2);  // 2 MB fp8
  float* part = (float*)(ws + (size_t)N * D * 3);       // 64*192*128 f32
  int* cnt = (int*)(ws + (size_t)N * D * 3 + (size_t)64 * NSLOT * 128 * 4);
  int* list = cnt + 128;                                // NCLS*256 ints

  hipMemsetAsync(cnt, 0, 128 * 4, stream);
  hipMemsetAsync(out, 0, sizeof(float), stream);

  normalize_kernel<<<N / 4, 256, 0, stream>>>(emb, label, abf, a8, cnt, list);

  // One block per 2-tile strip of the upper triangle: sum_y ceil((64-y)/2)
  // = 1056 blocks.
  simexp_rowsum_kernel<<<1056, 256, 0, stream>>>(a8, part);

  finalize_kernel<<<NCLS + N / 256, 256, 0, stream>>>(abf, part, label, cnt,
                                                      list, out);
}

// Round 13
// 134.299 us; speedup vs baseline: 1.1131x; 1.1131x over previous
//
#include <hip/hip_runtime.h>
#include <hip/hip_bf16.h>
#include <stdint.h>

#define N    8192
#define D    256
#define NCLS 100

static constexpr float TEMP    = 0.5f;
static constexpr float SCALE_F = 1.69864360f;  // sqrt(log2e/TEMP)
static constexpr float LN2     = 0.69314718055994531f;

// Partial slots (R13, 128-row bands, 64 bands, NSLOT=256):
//   row-side: tile (x, y=band), wave col-half jh -> slot 2x+jh (2y..127)
//   col-side: tile (x=band, y<=x), wave row-half wh -> slot 128+2y+wh
// Exact coverage: every tile writes its slots exactly once (diag tile's
// masked waves write zeros). Finalize sums 130 slots per band.
#define NSLOT 256

typedef float f32x4 __attribute__((ext_vector_type(4)));
typedef long  lx2  __attribute__((ext_vector_type(2)));

__device__ __forceinline__ unsigned short f2bf(float f) {
  union { float f; unsigned int u; } x; x.f = f;
  unsigned int r = x.u + 0x7fffu + ((x.u >> 16) & 1u);
  return (unsigned short)(r >> 16);
}
__device__ __forceinline__ float bf2f(unsigned short b) {
  union { unsigned int u; float f; } x; x.u = ((unsigned int)b) << 16;
  return x.f;
}

// fp8 fragment-PAIR-major layout: for row r, k:
//   kq = k>>6, kl = k&63, kkl = kl>>5, q = (kl>>3)&3
//   addr = (r>>4)*4096 + kq*1024 + q*256 + (r&15)*16 + kkl*8 + (k&7)
// -> lane (quad,l15)'s fragments for BOTH kkl halves of one kq are one
//    contiguous 16B: global_load_dwordx4, wave-contiguous 1024B segment.

// ---- Kernel A: row-normalize; bf16 row-major copy (class sums) + fp8 e4m3
// fragment-pair-major copy (GEMM).
__global__ __launch_bounds__(256) void normalize_kernel(
    const float* __restrict__ emb, const long long* __restrict__ label,
    unsigned short* __restrict__ abf, unsigned char* __restrict__ a8,
    int* __restrict__ cnt, int* __restrict__ list) {
  const int row  = blockIdx.x * 4 + (threadIdx.x >> 6);
  const int lane = threadIdx.x & 63;
  const float4 v = ((const float4*)(emb + (size_t)row * D))[lane];
  float ss = v.x * v.x + v.y * v.y + v.z * v.z + v.w * v.w;
#pragma unroll
  for (int off = 1; off < 64; off <<= 1) ss += __shfl_xor(ss, off);
  const float s = rsqrtf(ss) * SCALE_F;
  const float x = v.x * s, y = v.y * s, z = v.z * s, wv = v.w * s;

  ushort4 o;
  o.x = f2bf(x); o.y = f2bf(y); o.z = f2bf(z); o.w = f2bf(wv);
  ((ushort4*)(abf + (size_t)row * D))[lane] = o;

  int p = __builtin_amdgcn_cvt_pk_fp8_f32(x, y, 0, false);
  p = __builtin_amdgcn_cvt_pk_fp8_f32(z, wv, p, true);
  // k0 = lane*4: kq=lane>>4, q=(lane>>1)&3, kkl=(lane>>3)&1, k&7=(lane&1)*4
  *(int*)(a8 + (size_t)(row >> 4) * 4096 + (lane >> 4) * 1024 +
          ((lane >> 1) & 3) * 256 + (row & 15) * 16 + ((lane >> 3) & 1) * 8 +
          (lane & 1) * 4) = p;

  if (lane == 0) {
    const int c = (int)label[row];
    const int slot = atomicAdd(cnt + c, 1);
    list[c * 256 + slot] = row;
  }
}

// ---- Kernel B: symmetric (strict upper triangle). One block per 2-tile
// strip: band y x strip s covering col-tiles x0=y+2s, x1=x0+1. 1056
// blocks, 256 threads, pure-register (no LDS, no barriers).
//
// R13 (pipelined strip-2): R12's flaw was issuing tile-1 B loads AFTER
// tile-0's epilogue -> latency fully exposed. Now bG(tile1) issues right
// after tile-0's MFMAs, and tile-0's ~1300-cyc exp2/reduce epilogue is
// the latency blanket. A loaded once for both tiles: issued bytes/block
// 192 KB vs R8's 2x128 KB (-25% -> L2-delivery term drops), and the
// load phases of co-resident blocks naturally stagger.
__global__ __launch_bounds__(256, 2) void simexp_rowsum_kernel(
    const unsigned char* __restrict__ A, float* __restrict__ part) {
  const int tid  = threadIdx.x;
  const int w    = tid >> 6;
  const int lane = tid & 63;
  const int quad = lane >> 4;
  const int l15  = lane & 15;

  // Strip decode: band y has (65-y)>>1 strips.
  const int b = blockIdx.x;
  int y = 0, c = 0;
  while (c + ((65 - y) >> 1) <= b) { c += (65 - y) >> 1; ++y; }
  const int s = b - c;
  const int x0 = y + 2 * s;
  const bool has1 = (x0 + 1 < 64);
  const bool dmask = (s == 0);  // tile0 is the diagonal tile

  const int wm  = (w & 1) * 64;   // wave's row half
  const int jn0 = (w >> 1) * 64;  // wave's col half
  const int jh  = jn0 >> 6;
  const int wh  = wm >> 6;
  const int lo  = quad * 256 + l15 * 16;

  const unsigned char* Ap = A + (size_t)(y * 8 + (w & 1) * 4) * 4096;

  // A fragments: loaded once, reused for both tiles.
  lx2 aF[4][4];
#pragma unroll
  for (int mt = 0; mt < 4; ++mt)
#pragma unroll
    for (int kq = 0; kq < 4; ++kq)
      aF[mt][kq] = *(const lx2*)(Ap + mt * 4096 + kq * 1024 + lo);

  // B fragments for tile 0.
  const unsigned char* Bp0 = A + (size_t)(x0 * 8 + (w >> 1) * 4) * 4096;
  lx2 bF[4][4];
#pragma unroll
  for (int nt = 0; nt < 4; ++nt)
#pragma unroll
    for (int kq = 0; kq < 4; ++kq)
      bF[nt][kq] = *(const lx2*)(Bp0 + nt * 4096 + kq * 1024 + lo);

  // MFMA tile 0.
  f32x4 acc[4][4];
#pragma unroll
  for (int mt = 0; mt < 4; ++mt)
#pragma unroll
    for (int nt = 0; nt < 4; ++nt) acc[mt][nt] = (f32x4){0.f, 0.f, 0.f, 0.f};
#pragma unroll
  for (int kq = 0; kq < 4; ++kq)
#pragma unroll
    for (int kkl = 0; kkl < 2; ++kkl)
#pragma unroll
      for (int mt = 0; mt < 4; ++mt)
#pragma unroll
        for (int nt = 0; nt < 4; ++nt)
          acc[mt][nt] = __builtin_amdgcn_mfma_f32_16x16x32_fp8_fp8(
              aF[mt][kq][kkl], bF[nt][kq][kkl], acc[mt][nt], 0, 0, 0);

  // Issue tile-1 B loads NOW; they fly under tile-0's epilogue.
  lx2 bG[4][4];
  if (has1) {
    const unsigned char* Bp1 = Bp0 + 8 * 4096;
#pragma unroll
    for (int nt = 0; nt < 4; ++nt)
#pragma unroll
      for (int kq = 0; kq < 4; ++kq)
        bG[nt][kq] = *(const lx2*)(Bp1 + nt * 4096 + kq * 1024 + lo);
  }

  // ---- epilogue tile 0 (the latency blanket) ----
  {
    float rowpart[4][4];
    float colpart[4] = {0.f, 0.f, 0.f, 0.f};
#pragma unroll
    for (int mt = 0; mt < 4; ++mt)
#pragma unroll
      for (int e = 0; e < 4; ++e) rowpart[mt][e] = 0.f;
#pragma unroll
    for (int mt = 0; mt < 4; ++mt)
#pragma unroll
      for (int nt = 0; nt < 4; ++nt)
#pragma unroll
        for (int e = 0; e < 4; ++e) {
          float v = __builtin_amdgcn_exp2f(acc[mt][nt][e]);
          if (dmask) {
            const int iw = wm + mt * 16 + quad * 4 + e;  // row in 128-tile
            const int jw = jn0 + nt * 16 + l15;          // col in 128-tile
            v = (iw < jw) ? v : 0.f;
          }
          rowpart[mt][e] += v;
          colpart[nt] += v;
        }
    float* coldst =
        part + ((size_t)x0 * NSLOT + 128 + 2 * y + wh) * 128 + jn0;
#pragma unroll
    for (int nt = 0; nt < 4; ++nt) {
      float v = colpart[nt];
      v += __shfl_xor(v, 16);
      v += __shfl_xor(v, 32);
      if (quad == 0) coldst[nt * 16 + l15] = v;
    }
    float* rowdst = part + ((size_t)y * NSLOT + 2 * x0 + jh) * 128 + wm;
#pragma unroll
    for (int mt = 0; mt < 4; ++mt)
#pragma unroll
      for (int e = 0; e < 4; ++e) {
        float v = rowpart[mt][e];
        v += __shfl_xor(v, 1);
        v += __shfl_xor(v, 2);
        v += __shfl_xor(v, 4);
        v += __shfl_xor(v, 8);
        if (l15 == 0) rowdst[mt * 16 + quad * 4 + e] = v;
      }
  }

  if (!has1) return;

  // ---- MFMA tile 1 (bG already resident) ----
#pragma unroll
  for (int mt = 0; mt < 4; ++mt)
#pragma unroll
    for (int nt = 0; nt < 4; ++nt) acc[mt][nt] = (f32x4){0.f, 0.f, 0.f, 0.f};
#pragma unroll
  for (int kq = 0; kq < 4; ++kq)
#pragma unroll
    for (int kkl = 0; kkl < 2; ++kkl)
#pragma unroll
      for (int mt = 0; mt < 4; ++mt)
#pragma unroll
        for (int nt = 0; nt < 4; ++nt)
          acc[mt][nt] = __builtin_amdgcn_mfma_f32_16x16x32_fp8_fp8(
              aF[mt][kq][kkl], bG[nt][kq][kkl], acc[mt][nt], 0, 0, 0);

  // ---- epilogue tile 1 (never diagonal: x1 > y) ----
  {
    const int x1 = x0 + 1;
    float rowpart[4][4];
    float colpart[4] = {0.f, 0.f, 0.f, 0.f};
#pragma unroll
    for (int mt = 0; mt < 4; ++mt)
#pragma unroll
      for (int e = 0; e < 4; ++e) rowpart[mt][e] = 0.f;
#pragma unroll
    for (int mt = 0; mt < 4; ++mt)
#pragma unroll
      for (int nt = 0; nt < 4; ++nt)
#pragma unroll
        for (int e = 0; e < 4; ++e) {
          float v = __builtin_amdgcn_exp2f(acc[mt][nt][e]);
          rowpart[mt][e] += v;
          colpart[nt] += v;
        }
    float* coldst =
        part + ((size_t)x1 * NSLOT + 128 + 2 * y + wh) * 128 + jn0;
#pragma unroll
    for (int nt = 0; nt < 4; ++nt) {
      float v = colpart[nt];
      v += __shfl_xor(v, 16);
      v += __shfl_xor(v, 32);
      if (quad == 0) coldst[nt * 16 + l15] = v;
    }
    float* rowdst = part + ((size_t)y * NSLOT + 2 * x1 + jh) * 128 + wm;
#pragma unroll
    for (int mt = 0; mt < 4; ++mt)
#pragma unroll
      for (int e = 0; e < 4; ++e) {
        float v = rowpart[mt][e];
        v += __shfl_xor(v, 1);
        v += __shfl_xor(v, 2);
        v += __shfl_xor(v, 4);
        v += __shfl_xor(v, 8);
        if (l15 == 0) rowdst[mt * 16 + quad * 4 + e] = v;
      }
  }
}

__global__ __launch_bounds__(256) void finalize_kernel(
    const unsigned short* __restrict__ abf, const float* __restrict__ part,
    const long long* __restrict__ label, const int* __restrict__ cnt,
    const int* __restrict__ list, float* __restrict__ out) {
  __shared__ float red[4];
  __shared__ int rows_l[256];
  const int tid  = threadIdx.x;
  const int w    = tid >> 6;
  const int lane = tid & 63;

  if (blockIdx.x < NCLS) {
    const int c = blockIdx.x;
    const int m = cnt[c];
    if (m <= 1) return;
    if (tid < m) rows_l[tid] = list[c * 256 + tid];
    __syncthreads();
    float acc = 0.f;
    for (int s = 0; s < m; ++s)
      acc += bf2f(abf[(size_t)rows_l[s] * D + tid]);
    float v = acc * acc;
#pragma unroll
    for (int off = 1; off < 64; off <<= 1) v += __shfl_xor(v, off);
    if (lane == 0) red[w] = v;
    __syncthreads();
    if (tid == 0) {
      const float ssq = red[0] + red[1] + red[2] + red[3];
      const float term = (ssq * LN2 - 2.0f * (float)m) / (float)(m - 1);
      atomicAdd(out, -term);
    }
  } else {
    // rowsum_i = sum of this band's 130 written slots:
    //   row-side slots 2*band..127, col-side slots 128..129+2*band.
    const int i = (blockIdx.x - NCLS) * 256 + tid;
    const int band = i >> 7, r = i & 127;
    const float* ps = part + (size_t)band * NSLOT * 128 + r;
    float rs = 0.f;
#pragma unroll 4
    for (int s2 = 2 * band; s2 < 128; ++s2) rs += ps[(size_t)s2 * 128];
#pragma unroll 4
    for (int u = 128; u < 130 + 2 * band; ++u) rs += ps[(size_t)u * 128];
    const int c = (int)label[i];
    float v = 0.f;
    if (cnt[c] > 1)
      v = __builtin_amdgcn_logf(rs) * LN2;
#pragma unroll
    for (int off = 1; off < 64; off <<= 1) v += __shfl_xor(v, off);
    if (lane == 0) red[w] = v;
    __syncthreads();
    if (tid == 0)
      atomicAdd(out, red[0] + red[1] + red[2] + red[3]);
  }
}

extern "C" void kernel_launch(void* const* d_in, const int* in_sizes, int n_in,
                              void* d_out, int out_size, void* d_ws,
                              size_t ws_size, hipStream_t stream) {
  const float* emb = (const float*)d_in[0];
  const long long* label = (const long long*)d_in[1];
  float* out = (float*)d_out;

  char* ws = (char*)d_ws;
  unsigned short* abf = (unsigned short*)ws;            // 4 MB bf16 row-major
  unsigned char* a8 = (unsigned char*)(ws + (size_t)N * D * 2);  // 2 MB fp8
  float* part = (float*)(ws + (size_t)N * D * 3);       // 64*256*128 f32 (8MB)
  int* cnt = (int*)(ws + (size_t)N * D * 3 + (size_t)64 * NSLOT * 128 * 4);
  int* list = cnt + 128;                                // NCLS*256 ints

  hipMemsetAsync(cnt, 0, 128 * 4, stream);
  hipMemsetAsync(out, 0, sizeof(float), stream);

  normalize_kernel<<<N / 4, 256, 0, stream>>>(emb, label, abf, a8, cnt, list);

  // One block per 2-tile strip of the upper triangle: sum_y ceil((64-y)/2)
  // = 1056 blocks.
  simexp_rowsum_kernel<<<1056, 256, 0, stream>>>(a8, part);

  finalize_kernel<<<NCLS + N / 256, 256, 0, stream>>>(abf, part, label, cnt,
                                                      list, out);
}

// Round 15
// 127.048 us; speedup vs baseline: 1.1766x; 1.0571x over previous
//
#include <hip/hip_runtime.h>
#include <hip/hip_bf16.h>
#include <stdint.h>

#define N    8192
#define D    256
#define NCLS 100

static constexpr float TEMP    = 0.5f;
static constexpr float SCALE_F = 1.69864360f;  // sqrt(log2e/TEMP)
static constexpr float LN2     = 0.69314718055994531f;

// Per-band partial slots: 64 bands x 130 slots x 128 rows (see simexp).
#define NSLOT 130

typedef float f32x4 __attribute__((ext_vector_type(4)));
typedef long  lx2  __attribute__((ext_vector_type(2)));

__device__ __forceinline__ unsigned short f2bf(float f) {
  union { float f; unsigned int u; } x; x.f = f;
  unsigned int r = x.u + 0x7fffu + ((x.u >> 16) & 1u);
  return (unsigned short)(r >> 16);
}
__device__ __forceinline__ float bf2f(unsigned short b) {
  union { unsigned int u; float f; } x; x.u = ((unsigned int)b) << 16;
  return x.f;
}

// fp8 fragment-PAIR-major layout: for row r, k:
//   kq = k>>6, kl = k&63, kkl = kl>>5, q = (kl>>3)&3
//   addr = (r>>4)*4096 + kq*1024 + q*256 + (r&15)*16 + kkl*8 + (k&7)
// -> lane (quad,l15)'s fragments for BOTH kkl halves of one kq are one
//    contiguous 16B: global_load_dwordx4, wave-contiguous 1024B segment.

// ---- Kernel A: row-normalize; bf16 row-major copy (class sums) + fp8 e4m3
// fragment-pair-major copy (GEMM).
__global__ __launch_bounds__(256) void normalize_kernel(
    const float* __restrict__ emb, const long long* __restrict__ label,
    unsigned short* __restrict__ abf, unsigned char* __restrict__ a8,
    int* __restrict__ cnt, int* __restrict__ list) {
  const int row  = blockIdx.x * 4 + (threadIdx.x >> 6);
  const int lane = threadIdx.x & 63;
  const float4 v = ((const float4*)(emb + (size_t)row * D))[lane];
  float ss = v.x * v.x + v.y * v.y + v.z * v.z + v.w * v.w;
#pragma unroll
  for (int off = 1; off < 64; off <<= 1) ss += __shfl_xor(ss, off);
  const float s = rsqrtf(ss) * SCALE_F;
  const float x = v.x * s, y = v.y * s, z = v.z * s, wv = v.w * s;

  ushort4 o;
  o.x = f2bf(x); o.y = f2bf(y); o.z = f2bf(z); o.w = f2bf(wv);
  ((ushort4*)(abf + (size_t)row * D))[lane] = o;

  int p = __builtin_amdgcn_cvt_pk_fp8_f32(x, y, 0, false);
  p = __builtin_amdgcn_cvt_pk_fp8_f32(z, wv, p, true);
  // k0 = lane*4: kq=lane>>4, q=(lane>>1)&3, kkl=(lane>>3)&1, k&7=(lane&1)*4
  *(int*)(a8 + (size_t)(row >> 4) * 4096 + (lane >> 4) * 1024 +
          ((lane >> 1) & 3) * 256 + (row & 15) * 16 + ((lane >> 3) & 1) * 8 +
          (lane & 1) * 4) = p;

  if (lane == 0) {
    const int c = (int)label[row];
    const int slot = atomicAdd(cnt + c, 1);
    list[c * 256 + slot] = row;
  }
}

struct TileCoord { int x, y; };
__device__ __forceinline__ TileCoord tri_decode(int b) {
  int x = (int)((-1.0f + sqrtf(1.0f + 8.0f * (float)b)) * 0.5f);
  while ((x + 1) * (x + 2) / 2 <= b) ++x;
  while (x * (x + 1) / 2 > b) --x;
  return {x, b - x * (x + 1) / 2};
}

// ---- Kernel B: symmetric (strict upper triangle), one block per live
// 128x128 sub-tile (2080 blocks), all operands in registers, no LDS, no
// barriers. Identical to R8 except for ONE change:
//
// R14 (anti-load-sinking fence): R13's counters exposed the real enemy —
// VGPR_Count=116 for a kernel declaring ~260 live operand regs means the
// compiler SANK the loads into their uses (rematerialized load->wait->use
// chains, MLP~1-2, ~200-400 cyc exposed L2 latency per group). That one
// fact explains the 30-48 us plateau across R4-R13. Fix: issue all 32
// loads in use-order (kq-major), then __builtin_amdgcn_sched_barrier(0)
// — the scheduler cannot move loads past the fence, so all 32 stay
// issued up-front (VGPR ~200-235, fits 256 cap at 2 waves/SIMD) and the
// progressive vmcnt waits release each kq group with 24 younger loads
// still in flight under the MFMAs (counted-vmcnt via one intrinsic).
//
// Partial-sum slot map (bijective, plain stores, no atomics) — band t:
//   row-side, block (x,t), wave col-half jh -> slot 2x+jh   (slots 2t..127)
//   col-side, block (t,y<t), wave row-half rh -> slot 2y+rh (slots 0..2t-1)
//   col-side of diagonal block (t,t) -> slots 128+rh
// Every (band, slot, idx) written exactly once (diag dead wave writes 0s).
__global__ __launch_bounds__(256, 2) void simexp_rowsum_kernel(
    const unsigned char* __restrict__ A, float* __restrict__ part) {
  const int tid  = threadIdx.x;
  const int w    = tid >> 6;
  const int lane = tid & 63;
  const int quad = lane >> 4;
  const int l15  = lane & 15;

  const TileCoord tc = tri_decode(blockIdx.x);
  const int x = tc.x, y = tc.y;
  const int row0 = y << 7;
  const int col0 = x << 7;
  const bool diag = (x == y);
  const int wm  = (w & 1) * 64;   // wave's row half
  const int jn0 = (w >> 1) * 64;  // wave's col half

  // Diagonal sub-tile, wave region entirely strictly-lower (only w=1):
  // contributes nothing; fill its partial slots (coverage invariant).
  if (diag && wm > jn0) {
    part[((size_t)y * NSLOT + 2 * x) * 128 + 64 + lane] = 0.f;  // row-side
    part[((size_t)x * NSLOT + 129) * 128 + lane] = 0.f;         // col-side
    return;
  }
  const bool needmask = diag && (wm == jn0);

  const unsigned char* Ap = A + (size_t)((row0 >> 4) + (w & 1) * 4) * 4096;
  const unsigned char* Bp = A + (size_t)((col0 >> 4) + (w >> 1) * 4) * 4096;
  const int lo = quad * 256 + l15 * 16;

  // Issue ALL 32 operand loads, in use order (kq-major: oldest = first
  // consumed, so progressive vmcnt releases early groups first).
  lx2 aF[4][4], bF[4][4];  // [panel][kq] -> {kkl0 frag, kkl1 frag}
#pragma unroll
  for (int kq = 0; kq < 4; ++kq) {
#pragma unroll
    for (int mt = 0; mt < 4; ++mt)
      aF[mt][kq] = *(const lx2*)(Ap + mt * 4096 + kq * 1024 + lo);
#pragma unroll
    for (int nt = 0; nt < 4; ++nt)
      bF[nt][kq] = *(const lx2*)(Bp + nt * 4096 + kq * 1024 + lo);
  }

  // THE fence: loads above may not sink below; MFMAs below may not hoist
  // above. Forces all 32 loads in flight before the first MFMA wait.
  __builtin_amdgcn_sched_barrier(0);

  f32x4 acc[4][4];
#pragma unroll
  for (int mt = 0; mt < 4; ++mt)
#pragma unroll
    for (int nt = 0; nt < 4; ++nt) acc[mt][nt] = (f32x4){0.f, 0.f, 0.f, 0.f};

  // 128 pure-register MFMAs.
#pragma unroll
  for (int kq = 0; kq < 4; ++kq)
#pragma unroll
    for (int kkl = 0; kkl < 2; ++kkl)
#pragma unroll
      for (int mt = 0; mt < 4; ++mt)
#pragma unroll
        for (int nt = 0; nt < 4; ++nt)
          acc[mt][nt] = __builtin_amdgcn_mfma_f32_16x16x32_fp8_fp8(
              aF[mt][kq][kkl], bF[nt][kq][kkl], acc[mt][nt], 0, 0, 0);

  // Epilogue: exp2, diagonal mask, row partials + column partials.
  float rowpart[4][4];
  float colpart[4] = {0.f, 0.f, 0.f, 0.f};
#pragma unroll
  for (int mt = 0; mt < 4; ++mt)
#pragma unroll
    for (int e = 0; e < 4; ++e) rowpart[mt][e] = 0.f;
#pragma unroll
  for (int mt = 0; mt < 4; ++mt)
#pragma unroll
    for (int nt = 0; nt < 4; ++nt)
#pragma unroll
      for (int e = 0; e < 4; ++e) {
        float v = __builtin_amdgcn_exp2f(acc[mt][nt][e]);
        if (needmask) {
          const int iw = mt * 16 + quad * 4 + e;  // row within wave region
          const int jw = nt * 16 + l15;           // col within wave region
          v = (iw < jw) ? v : 0.f;
        }
        rowpart[mt][e] += v;
        colpart[nt] += v;
      }

  // Partial destinations (plain stores, each address written exactly once).
  const int rslot = 2 * x + (jn0 >> 6);
  const int cslot = diag ? (128 + (wm >> 6)) : (2 * y + (wm >> 6));
  float* rowdst = part + ((size_t)y * NSLOT + rslot) * 128 + wm;
  float* coldst = part + ((size_t)x * NSLOT + cslot) * 128 + jn0;

  // Column reduce over rows (lane bits 4,5): lanes quad==0 hold 16 cols.
#pragma unroll
  for (int nt = 0; nt < 4; ++nt) {
    float v = colpart[nt];
    v += __shfl_xor(v, 16);
    v += __shfl_xor(v, 32);
    if (quad == 0) coldst[nt * 16 + l15] = v;
  }
  // Row reduce over 16 cols (lane bits 0..3): lanes l15==0 (one per quad)
  // hold rows quad*4+e+mt*16.
#pragma unroll
  for (int mt = 0; mt < 4; ++mt)
#pragma unroll
    for (int e = 0; e < 4; ++e) {
      float v = rowpart[mt][e];
      v += __shfl_xor(v, 1);
      v += __shfl_xor(v, 2);
      v += __shfl_xor(v, 4);
      v += __shfl_xor(v, 8);
      if (l15 == 0) rowdst[mt * 16 + quad * 4 + e] = v;
    }
}

__global__ __launch_bounds__(256) void finalize_kernel(
    const unsigned short* __restrict__ abf, const float* __restrict__ part,
    const long long* __restrict__ label, const int* __restrict__ cnt,
    const int* __restrict__ list, float* __restrict__ out) {
  __shared__ float red[4];
  __shared__ int rows_l[256];
  const int tid  = threadIdx.x;
  const int w    = tid >> 6;
  const int lane = tid & 63;

  if (blockIdx.x < NCLS) {
    const int c = blockIdx.x;
    const int m = cnt[c];
    if (m <= 1) return;
    if (tid < m) rows_l[tid] = list[c * 256 + tid];
    __syncthreads();
    float acc = 0.f;
    for (int s = 0; s < m; ++s)
      acc += bf2f(abf[(size_t)rows_l[s] * D + tid]);
    float v = acc * acc;
#pragma unroll
    for (int off = 1; off < 64; off <<= 1) v += __shfl_xor(v, off);
    if (lane == 0) red[w] = v;
    __syncthreads();
    if (tid == 0) {
      const float ssq = red[0] + red[1] + red[2] + red[3];
      const float term = (ssq * LN2 - 2.0f * (float)m) / (float)(m - 1);
      atomicAdd(out, -term);
    }
  } else {
    // rowsum_i = sum of the 130 per-block partials for this row's band.
    const int i = (blockIdx.x - NCLS) * 256 + tid;
    const int band = i >> 7, r = i & 127;
    const float* ps = part + (size_t)band * NSLOT * 128 + r;
    float rs = 0.f;
#pragma unroll 13
    for (int s = 0; s < NSLOT; ++s) rs += ps[(size_t)s * 128];
    const int c = (int)label[i];
    float v = 0.f;
    if (cnt[c] > 1)
      v = __builtin_amdgcn_logf(rs) * LN2;
#pragma unroll
    for (int off = 1; off < 64; off <<= 1) v += __shfl_xor(v, off);
    if (lane == 0) red[w] = v;
    __syncthreads();
    if (tid == 0)
      atomicAdd(out, red[0] + red[1] + red[2] + red[3]);
  }
}

extern "C" void kernel_launch(void* const* d_in, const int* in_sizes, int n_in,
                              void* d_out, int out_size, void* d_ws,
                              size_t ws_size, hipStream_t stream) {
  const float* emb = (const float*)d_in[0];
  const long long* label = (const long long*)d_in[1];
  float* out = (float*)d_out;

  char* ws = (char*)d_ws;
  unsigned short* abf = (unsigned short*)ws;            // 4 MB bf16 row-major
  unsigned char* a8 = (unsigned char*)(ws + (size_t)N * D * 2);  // 2 MB fp8
  float* part = (float*)(ws + (size_t)N * D * 3);       // 64*130*128 f32
  int* cnt = (int*)(ws + (size_t)N * D * 3 + (size_t)64 * NSLOT * 128 * 4);
  int* list = cnt + 128;                                // NCLS*256 ints

  hipMemsetAsync(cnt, 0, 128 * 4, stream);
  hipMemsetAsync(out, 0, sizeof(float), stream);

  normalize_kernel<<<N / 4, 256, 0, stream>>>(emb, label, abf, a8, cnt, list);

  // One block per live upper-triangle 128x128 sub-tile: 64*65/2 = 2080.
  simexp_rowsum_kernel<<<2080, 256, 0, stream>>>(a8, part);

  finalize_kernel<<<NCLS + N / 256, 256, 0, stream>>>(abf, part, label, cnt,
                                                      list, out);
}

// Round 16
// 124.114 us; speedup vs baseline: 1.2044x; 1.0236x over previous
//
#include <hip/hip_runtime.h>
#include <hip/hip_bf16.h>
#include <stdint.h>

#define N    8192
#define D    256
#define NCLS 100

static constexpr float TEMP    = 0.5f;
static constexpr float SCALE_F = 1.69864360f;  // sqrt(log2e/TEMP)
static constexpr float LN2     = 0.69314718055994531f;

// Per-band partial slots: 64 bands x 130 slots x 128 rows (see simexp).
#define NSLOT 130

typedef float f32x4 __attribute__((ext_vector_type(4)));
typedef long  lx2  __attribute__((ext_vector_type(2)));

__device__ __forceinline__ unsigned short f2bf(float f) {
  union { float f; unsigned int u; } x; x.f = f;
  unsigned int r = x.u + 0x7fffu + ((x.u >> 16) & 1u);
  return (unsigned short)(r >> 16);
}
__device__ __forceinline__ float bf2f(unsigned short b) {
  union { unsigned int u; float f; } x; x.u = ((unsigned int)b) << 16;
  return x.f;
}

// fp8 fragment-PAIR-major layout (R8): for row r, k:
//   kq = k>>6, kl = k&63, kkl = kl>>5, q = (kl>>3)&3
//   addr = (r>>4)*4096 + kq*1024 + q*256 + (r&15)*16 + kkl*8 + (k&7)
// -> lane (quad,l15)'s A fragments for BOTH kkl halves of one kq are one
//    contiguous 16B: global_load_dwordx4, wave-contiguous 1024B segment.
//    The whole per-wave operand set is 4 panels x 4 kq x 16B = 128 VGPRs.

// ---- Kernel A: row-normalize; bf16 row-major copy (class sums) + fp8 e4m3
// fragment-pair-major copy (GEMM).
__global__ __launch_bounds__(256) void normalize_kernel(
    const float* __restrict__ emb, const long long* __restrict__ label,
    unsigned short* __restrict__ abf, unsigned char* __restrict__ a8,
    int* __restrict__ cnt, int* __restrict__ list) {
  const int row  = blockIdx.x * 4 + (threadIdx.x >> 6);
  const int lane = threadIdx.x & 63;
  const float4 v = ((const float4*)(emb + (size_t)row * D))[lane];
  float ss = v.x * v.x + v.y * v.y + v.z * v.z + v.w * v.w;
#pragma unroll
  for (int off = 1; off < 64; off <<= 1) ss += __shfl_xor(ss, off);
  const float s = rsqrtf(ss) * SCALE_F;
  const float x = v.x * s, y = v.y * s, z = v.z * s, wv = v.w * s;

  ushort4 o;
  o.x = f2bf(x); o.y = f2bf(y); o.z = f2bf(z); o.w = f2bf(wv);
  ((ushort4*)(abf + (size_t)row * D))[lane] = o;

  int p = __builtin_amdgcn_cvt_pk_fp8_f32(x, y, 0, false);
  p = __builtin_amdgcn_cvt_pk_fp8_f32(z, wv, p, true);
  // k0 = lane*4: kq=lane>>4, q=(lane>>1)&3, kkl=(lane>>3)&1, k&7=(lane&1)*4
  *(int*)(a8 + (size_t)(row >> 4) * 4096 + (lane >> 4) * 1024 +
          ((lane >> 1) & 3) * 256 + (row & 15) * 16 + ((lane >> 3) & 1) * 8 +
          (lane & 1) * 4) = p;

  if (lane == 0) {
    const int c = (int)label[row];
    const int slot = atomicAdd(cnt + c, 1);
    list[c * 256 + slot] = row;
  }
}

struct TileCoord { int x, y; };
__device__ __forceinline__ TileCoord tri_decode(int b) {
  int x = (int)((-1.0f + sqrtf(1.0f + 8.0f * (float)b)) * 0.5f);
  while ((x + 1) * (x + 2) / 2 <= b) ++x;
  while (x * (x + 1) / 2 > b) --x;
  return {x, b - x * (x + 1) / 2};
}

// ---- Kernel B: symmetric (strict upper triangle), one block per live
// 128x128 sub-tile (2080 blocks), all operands in registers, no LDS, no
// barriers. Best-measured variant of the session (121.1 us total).
//
// Session record (16 rounds): exp(sim) symmetry halves GEMM+exp2 work;
// pure-register operands beat LDS staging (R7 ablation: the LDS-fed MFMA
// loop itself was the wall); bijective plain-store partials beat 1M
// atomics; every further structural change (kq pipelining, 4 waves/SIMD,
// 256^2 tiles + skewed staging, strip-2 A-reuse, epilogue-blanket
// pipelining, sched_barrier anti-sink fence) REGRESSED vs this structure
// (122.8-149.5 vs 121.1). Residual: simexp ~30 us vs ~11 us ideal, an
// unexplained ~15 B/cyc/CU vmem delivery limit robust to all source-level
// interventions tried.
//
// Partial-sum slot map (bijective, plain stores, no atomics) — band t:
//   row-side, block (x,t), wave col-half jh -> slot 2x+jh   (slots 2t..127)
//   col-side, block (t,y<t), wave row-half rh -> slot 2y+rh (slots 0..2t-1)
//   col-side of diagonal block (t,t) -> slots 128+rh
// Every (band, slot, idx) written exactly once (diag dead wave writes 0s).
__global__ __launch_bounds__(256, 2) void simexp_rowsum_kernel(
    const unsigned char* __restrict__ A, float* __restrict__ part) {
  const int tid  = threadIdx.x;
  const int w    = tid >> 6;
  const int lane = tid & 63;
  const int quad = lane >> 4;
  const int l15  = lane & 15;

  const TileCoord tc = tri_decode(blockIdx.x);
  const int x = tc.x, y = tc.y;
  const int row0 = y << 7;
  const int col0 = x << 7;
  const bool diag = (x == y);
  const int wm  = (w & 1) * 64;   // wave's row half
  const int jn0 = (w >> 1) * 64;  // wave's col half

  // Diagonal sub-tile, wave region entirely strictly-lower (only w=1):
  // contributes nothing; fill its partial slots (coverage invariant).
  if (diag && wm > jn0) {
    part[((size_t)y * NSLOT + 2 * x) * 128 + 64 + lane] = 0.f;  // row-side
    part[((size_t)x * NSLOT + 129) * 128 + lane] = 0.f;         // col-side
    return;
  }
  const bool needmask = diag && (wm == jn0);

  const unsigned char* Ap = A + (size_t)((row0 >> 4) + (w & 1) * 4) * 4096;
  const unsigned char* Bp = A + (size_t)((col0 >> 4) + (w >> 1) * 4) * 4096;
  const int lo = quad * 256 + l15 * 16;

  // Load the full operand set into registers: 32 x dwordx4.
  lx2 aF[4][4], bF[4][4];  // [panel][kq] -> {kkl0 frag, kkl1 frag}
#pragma unroll
  for (int mt = 0; mt < 4; ++mt)
#pragma unroll
    for (int kq = 0; kq < 4; ++kq)
      aF[mt][kq] = *(const lx2*)(Ap + mt * 4096 + kq * 1024 + lo);
#pragma unroll
  for (int nt = 0; nt < 4; ++nt)
#pragma unroll
    for (int kq = 0; kq < 4; ++kq)
      bF[nt][kq] = *(const lx2*)(Bp + nt * 4096 + kq * 1024 + lo);

  f32x4 acc[4][4];
#pragma unroll
  for (int mt = 0; mt < 4; ++mt)
#pragma unroll
    for (int nt = 0; nt < 4; ++nt) acc[mt][nt] = (f32x4){0.f, 0.f, 0.f, 0.f};

  // 128 pure-register MFMAs.
#pragma unroll
  for (int kq = 0; kq < 4; ++kq)
#pragma unroll
    for (int kkl = 0; kkl < 2; ++kkl)
#pragma unroll
      for (int mt = 0; mt < 4; ++mt)
#pragma unroll
        for (int nt = 0; nt < 4; ++nt)
          acc[mt][nt] = __builtin_amdgcn_mfma_f32_16x16x32_fp8_fp8(
              aF[mt][kq][kkl], bF[nt][kq][kkl], acc[mt][nt], 0, 0, 0);

  // Epilogue: exp2, diagonal mask, row partials + column partials.
  float rowpart[4][4];
  float colpart[4] = {0.f, 0.f, 0.f, 0.f};
#pragma unroll
  for (int mt = 0; mt < 4; ++mt)
#pragma unroll
    for (int e = 0; e < 4; ++e) rowpart[mt][e] = 0.f;
#pragma unroll
  for (int mt = 0; mt < 4; ++mt)
#pragma unroll
    for (int nt = 0; nt < 4; ++nt)
#pragma unroll
      for (int e = 0; e < 4; ++e) {
        float v = __builtin_amdgcn_exp2f(acc[mt][nt][e]);
        if (needmask) {
          const int iw = mt * 16 + quad * 4 + e;  // row within wave region
          const int jw = nt * 16 + l15;           // col within wave region
          v = (iw < jw) ? v : 0.f;
        }
        rowpart[mt][e] += v;
        colpart[nt] += v;
      }

  // Partial destinations (plain stores, each address written exactly once).
  const int rslot = 2 * x + (jn0 >> 6);
  const int cslot = diag ? (128 + (wm >> 6)) : (2 * y + (wm >> 6));
  float* rowdst = part + ((size_t)y * NSLOT + rslot) * 128 + wm;
  float* coldst = part + ((size_t)x * NSLOT + cslot) * 128 + jn0;

  // Column reduce over rows (lane bits 4,5): lanes quad==0 hold 16 cols.
#pragma unroll
  for (int nt = 0; nt < 4; ++nt) {
    float v = colpart[nt];
    v += __shfl_xor(v, 16);
    v += __shfl_xor(v, 32);
    if (quad == 0) coldst[nt * 16 + l15] = v;
  }
  // Row reduce over 16 cols (lane bits 0..3): lanes l15==0 (one per quad)
  // hold rows quad*4+e+mt*16.
#pragma unroll
  for (int mt = 0; mt < 4; ++mt)
#pragma unroll
    for (int e = 0; e < 4; ++e) {
      float v = rowpart[mt][e];
      v += __shfl_xor(v, 1);
      v += __shfl_xor(v, 2);
      v += __shfl_xor(v, 4);
      v += __shfl_xor(v, 8);
      if (l15 == 0) rowdst[mt * 16 + quad * 4 + e] = v;
    }
}

__global__ __launch_bounds__(256) void finalize_kernel(
    const unsigned short* __restrict__ abf, const float* __restrict__ part,
    const long long* __restrict__ label, const int* __restrict__ cnt,
    const int* __restrict__ list, float* __restrict__ out) {
  __shared__ float red[4];
  __shared__ int rows_l[256];
  const int tid  = threadIdx.x;
  const int w    = tid >> 6;
  const int lane = tid & 63;

  if (blockIdx.x < NCLS) {
    const int c = blockIdx.x;
    const int m = cnt[c];
    if (m <= 1) return;
    if (tid < m) rows_l[tid] = list[c * 256 + tid];
    __syncthreads();
    float acc = 0.f;
    for (int s = 0; s < m; ++s)
      acc += bf2f(abf[(size_t)rows_l[s] * D + tid]);
    float v = acc * acc;
#pragma unroll
    for (int off = 1; off < 64; off <<= 1) v += __shfl_xor(v, off);
    if (lane == 0) red[w] = v;
    __syncthreads();
    if (tid == 0) {
      const float ssq = red[0] + red[1] + red[2] + red[3];
      const float term = (ssq * LN2 - 2.0f * (float)m) / (float)(m - 1);
      atomicAdd(out, -term);
    }
  } else {
    // rowsum_i = sum of the 130 per-block partials for this row's band.
    const int i = (blockIdx.x - NCLS) * 256 + tid;
    const int band = i >> 7, r = i & 127;
    const float* ps = part + (size_t)band * NSLOT * 128 + r;
    float rs = 0.f;
#pragma unroll 13
    for (int s = 0; s < NSLOT; ++s) rs += ps[(size_t)s * 128];
    const int c = (int)label[i];
    float v = 0.f;
    if (cnt[c] > 1)
      v = __builtin_amdgcn_logf(rs) * LN2;
#pragma unroll
    for (int off = 1; off < 64; off <<= 1) v += __shfl_xor(v, off);
    if (lane == 0) red[w] = v;
    __syncthreads();
    if (tid == 0)
      atomicAdd(out, red[0] + red[1] + red[2] + red[3]);
  }
}

extern "C" void kernel_launch(void* const* d_in, const int* in_sizes, int n_in,
                              void* d_out, int out_size, void* d_ws,
                              size_t ws_size, hipStream_t stream) {
  const float* emb = (const float*)d_in[0];
  const long long* label = (const long long*)d_in[1];
  float* out = (float*)d_out;

  char* ws = (char*)d_ws;
  unsigned short* abf = (unsigned short*)ws;            // 4 MB bf16 row-major
  unsigned char* a8 = (unsigned char*)(ws + (size_t)N * D * 2);  // 2 MB fp8
  float* part = (float*)(ws + (size_t)N * D * 3);       // 64*130*128 f32
  int* cnt = (int*)(ws + (size_t)N * D * 3 + (size_t)64 * NSLOT * 128 * 4);
  int* list = cnt + 128;                                // NCLS*256 ints

  hipMemsetAsync(cnt, 0, 128 * 4, stream);
  hipMemsetAsync(out, 0, sizeof(float), stream);

  normalize_kernel<<<N / 4, 256, 0, stream>>>(emb, label, abf, a8, cnt, list);

  // One block per live upper-triangle 128x128 sub-tile: 64*65/2 = 2080.
  simexp_rowsum_kernel<<<2080, 256, 0, stream>>>(a8, part);

  finalize_kernel<<<NCLS + N / 256, 256, 0, stream>>>(abf, part, label, cnt,
                                                      list, out);
}